// Round 8
// baseline (805.628 us; speedup 1.0000x reference)
//
#include <hip/hip_runtime.h>
#include <math.h>

// B=64, I=4096, C=32, D=d=16
#define ITILES 256
#define IPB    16    // i's per itile

// ---------------------------------------------------------------------------
// R8: coalesced W staging (the R7 lesson: global_load_lds gather = 64
// lines/wave-inst was the per-iter stall; coalesced dwordx4 = 16 lines).
// Grid = 512 blocks: itile = blockIdx>>1, half = blockIdx&1.
// Block = 512 thr = 8 waves; wave owns 4 batches b = half*32 + wave*4.
// Lane: c = lane&31, h = lane>>5 (D0 = 8h).
//
// LDS: XOR layout, float4 units: W4[c*64+r] lives at slot r*32 + (c^(r&31)).
//  - staging write (thread tid, chunk k): g = k*512+tid -> c'=k*8+wave
//    (uniform), r=lane -> slot = lane*32 + ((lane&31)^c'). Lanes spread over
//    all banks -> conflict-free ds_write_b128.
//  - compute read (j,dblk): u1 = 4j+dblk, addr = h*1024 + u1*32 + (u1^c).
//    Lanes spread over all banks -> conflict-free ds_read_b128 (+2 VALU).
// Pipeline (ONE barrier/iter): ds_write R->buf[ii&1]; barrier;
// global R<-W(i+1); compute buf[ii&1].  buf[ii&1] was last read in iter
// ii-2, strictly before barrier ii-1 -> safe.
//
// x rides scalar loads (wave-uniform addresses). v re-read per iter
// (anti-hoisted) to keep regs ~<128: u32 + s_acc32 + R16 + temps.
// USE_V=0: slab = sum_i u (uniform c folded into reduce scale).
// USE_V=1: p = u.vg -> softmax over c (no max-sub; |p| bounded) ->
//          slab = sum_i c_ij*u.
// ---------------------------------------------------------------------------
template<int USE_V>
__global__ __launch_bounds__(512, 4)   // 128-VGPR budget, 4 waves/SIMD
void pass_kernel(const float* __restrict__ Wg, const float* __restrict__ xg,
                 const float* __restrict__ vg, float* __restrict__ slab)
{
    __shared__ float4 lds_w[2][2048];   // 2 x 32 KB

    const int tid   = threadIdx.x;
    const int wave  = tid >> 6;
    const int lane  = tid & 63;
    const int c     = lane & 31;
    const int h     = lane >> 5;
    const int D0    = h * 8;
    const int itile = blockIdx.x >> 1;
    const int half  = blockIdx.x & 1;
    const int i0    = itile * IPB;
    const int b0    = half * 32 + wave * 4;
    const int b0u   = __builtin_amdgcn_readfirstlane(b0);

    const float4* W4 = (const float4*)Wg;

    // staging write slots (float4 units), one per chunk k
    int wslot[4];
    #pragma unroll
    for (int k = 0; k < 4; ++k) {
        const int cp = k * 8 + wave;            // = g>>6, uniform per wave
        wslot[k] = lane * 32 + ((lane & 31) ^ cp);
    }

    // ---- preload W(i0) coalesced into regs
    float4 R[4];
    #pragma unroll
    for (int k = 0; k < 4; ++k)
        R[k] = W4[(size_t)i0 * 2048 + k * 512 + tid];

    float s_acc[8][4];   // [j][bb]
    #pragma unroll
    for (int j = 0; j < 8; ++j)
        #pragma unroll
        for (int bb = 0; bb < 4; ++bb) s_acc[j][bb] = 0.f;

    const float* vgl = vg;   // redefined opaquely each iter: blocks LICM hoist

    for (int ii = 0; ii < IPB; ++ii) {
        const int i = i0 + ii;

        // ---- stage W(i) regs -> buf[ii&1] (conflict-free swizzled writes)
        float4* bw = lds_w[ii & 1];
        #pragma unroll
        for (int k = 0; k < 4; ++k)
            bw[wslot[k]] = R[k];

        __syncthreads();   // buf[ii&1] complete; (buf[(ii+1)&1] free: last read ii-1)

        // ---- issue coalesced loads for W(i+1); land during compute below
        if (ii + 1 < IPB) {
            #pragma unroll
            for (int k = 0; k < 4; ++k)
                R[k] = W4[(size_t)(i + 1) * 2048 + k * 512 + tid];
        }

        const float4* br = lds_w[ii & 1];
        const float* xb = xg + (size_t)b0u * 65536 + (size_t)i * 16;

        if (USE_V == 0) {
            // ---- accumulate straight into s_acc (no u array)
            #pragma unroll
            for (int dblk = 0; dblk < 4; ++dblk) {
                float4 xs[4];   // wave-uniform -> scalar loads (SGPRs)
                #pragma unroll
                for (int bb = 0; bb < 4; ++bb)
                    xs[bb] = *(const float4*)(xb + (size_t)bb * 65536 + dblk * 4);
                #pragma unroll
                for (int j = 0; j < 8; ++j) {
                    const int u1 = 4 * j + dblk;
                    float4 wv = br[h * 1024 + u1 * 32 + (u1 ^ c)];
                    #pragma unroll
                    for (int bb = 0; bb < 4; ++bb) {
                        s_acc[j][bb] = fmaf(wv.x, xs[bb].x, s_acc[j][bb]);
                        s_acc[j][bb] = fmaf(wv.y, xs[bb].y, s_acc[j][bb]);
                        s_acc[j][bb] = fmaf(wv.z, xs[bb].z, s_acc[j][bb]);
                        s_acc[j][bb] = fmaf(wv.w, xs[bb].w, s_acc[j][bb]);
                    }
                }
            }
        } else {
            // ---- u_hat: u[j][bb] = sum_d W[c, D0+j, d] * x[b0+bb, i, d]
            float u[8][4];
            #pragma unroll
            for (int j = 0; j < 8; ++j)
                #pragma unroll
                for (int bb = 0; bb < 4; ++bb) u[j][bb] = 0.f;

            #pragma unroll
            for (int dblk = 0; dblk < 4; ++dblk) {
                float4 xs[4];
                #pragma unroll
                for (int bb = 0; bb < 4; ++bb)
                    xs[bb] = *(const float4*)(xb + (size_t)bb * 65536 + dblk * 4);
                #pragma unroll
                for (int j = 0; j < 8; ++j) {
                    const int u1 = 4 * j + dblk;
                    float4 wv = br[h * 1024 + u1 * 32 + (u1 ^ c)];
                    #pragma unroll
                    for (int bb = 0; bb < 4; ++bb) {
                        u[j][bb] = fmaf(wv.x, xs[bb].x, u[j][bb]);
                        u[j][bb] = fmaf(wv.y, xs[bb].y, u[j][bb]);
                        u[j][bb] = fmaf(wv.z, xs[bb].z, u[j][bb]);
                        u[j][bb] = fmaf(wv.w, xs[bb].w, u[j][bb]);
                    }
                }
            }

            // ---- v re-read (L2-hot, loop-invariant but NOT reg-hoisted)
            asm volatile("" : "+r"(vgl));
            // ---- routing: p -> softmax over c (no max-sub) -> s_acc += c_ij*u
            #pragma unroll
            for (int bb = 0; bb < 4; ++bb) {
                const float* vp = vgl + (size_t)(b0 + bb) * 512 + (size_t)(c * 16 + D0);
                const float4 va = *(const float4*)vp;
                const float4 vb = *(const float4*)(vp + 4);
                float p = 0.f;
                p = fmaf(u[0][bb], va.x, p); p = fmaf(u[1][bb], va.y, p);
                p = fmaf(u[2][bb], va.z, p); p = fmaf(u[3][bb], va.w, p);
                p = fmaf(u[4][bb], vb.x, p); p = fmaf(u[5][bb], vb.y, p);
                p = fmaf(u[6][bb], vb.z, p); p = fmaf(u[7][bb], vb.w, p);
                p += __shfl_xor(p, 32);   // combine D-halves (lanes l, l^32 share c)
                // |p| <= |u||v| ~ 12 -> exp safe without max subtraction
                float e = __expf(p);
                float t = e;
                t += __shfl_xor(t, 16);
                t += __shfl_xor(t, 8);
                t += __shfl_xor(t, 4);
                t += __shfl_xor(t, 2);
                t += __shfl_xor(t, 1);
                float cij = __fdividef(e, t);
                #pragma unroll
                for (int j = 0; j < 8; ++j)
                    s_acc[j][bb] = fmaf(cij, u[j][bb], s_acc[j][bb]);
            }
        }
    }

    // ---- write per-itile partial slab (contiguous per (itile,b))
    float4* slab4 = (float4*)slab;
    #pragma unroll
    for (int bb = 0; bb < 4; ++bb) {
        const int b = b0 + bb;
        size_t base = (size_t)itile * 8192 + (size_t)b * 128 + (size_t)(c * 4 + 2 * h);
        float4 lo = {s_acc[0][bb], s_acc[1][bb], s_acc[2][bb], s_acc[3][bb]};
        float4 hi = {s_acc[4][bb], s_acc[5][bb], s_acc[6][bb], s_acc[7][bb]};
        slab4[base]     = lo;
        slab4[base + 1] = hi;
    }
}

// ---------------------------------------------------------------------------
// Reduce 256 slabs -> s_j[b,c,D], squash -> out. If v1in != null, also emit
// vsum = out + v1in (pre-summed v12 for the next pass's u.(v1+v2) fold).
// ---------------------------------------------------------------------------
__global__ __launch_bounds__(256)
void reduce_squash(const float* __restrict__ slab, float* __restrict__ out, float scale,
                   const float* __restrict__ v1in, float* __restrict__ vsum)
{
    const int o = blockIdx.x * 256 + threadIdx.x;   // o = b*512 + c*16 + D
    float a[16];
    #pragma unroll
    for (int k = 0; k < 16; ++k) a[k] = 0.f;
    for (int g = 0; g < 16; ++g) {
        #pragma unroll
        for (int k = 0; k < 16; ++k)
            a[k] += slab[(size_t)(g * 16 + k) * 32768 + o];
    }
    float s = 0.f;
    #pragma unroll
    for (int k = 0; k < 16; ++k) s += a[k];
    s *= scale;
    float t = s * s;
    t += __shfl_xor(t, 1);
    t += __shfl_xor(t, 2);
    t += __shfl_xor(t, 4);
    t += __shfl_xor(t, 8);
    float r = s / (1.0f + t) / sqrtf(t + 1e-9f);
    out[o] = r;
    if (v1in) vsum[o] = r + v1in[o];
}

extern "C" void kernel_launch(void* const* d_in, const int* in_sizes, int n_in,
                              void* d_out, int out_size, void* d_ws, size_t ws_size,
                              hipStream_t stream)
{
    const float* x = (const float*)d_in[0];   // [64, 4096, 16]
    const float* W = (const float*)d_in[1];   // [1, 4096, 32, 16, 16]

    float* slab = (float*)d_ws;                     // 256 * 32768 floats = 32 MB
    float* v1   = slab + (size_t)ITILES * 32768;
    float* v2   = v1 + 32768;
    float* v12  = v2 + 32768;
    float* out  = (float*)d_out;

    // iter 1: uniform c (1/32 folded into reduce scale)
    hipLaunchKernelGGL((pass_kernel<0>), dim3(2 * ITILES), dim3(512), 0, stream, W, x, (const float*)nullptr, slab);
    hipLaunchKernelGGL(reduce_squash,    dim3(128),        dim3(256), 0, stream, slab, v1, 1.0f / 32.0f, (const float*)nullptr, (float*)nullptr);
    // iter 2: p = u.v1 ; reduce also emits v12 = v1 + v2
    hipLaunchKernelGGL((pass_kernel<1>), dim3(2 * ITILES), dim3(512), 0, stream, W, x, v1, slab);
    hipLaunchKernelGGL(reduce_squash,    dim3(128),        dim3(256), 0, stream, slab, v2, 1.0f, v1, v12);
    // iter 3: p = u.v1 + u.v2 = u.v12
    hipLaunchKernelGGL((pass_kernel<1>), dim3(2 * ITILES), dim3(512), 0, stream, W, x, v12, slab);
    hipLaunchKernelGGL(reduce_squash,    dim3(128),        dim3(256), 0, stream, slab, out, 1.0f, (const float*)nullptr, (float*)nullptr);
}

// Round 9
// 789.311 us; speedup vs baseline: 1.0207x; 1.0207x over previous
//
#include <hip/hip_runtime.h>
#include <math.h>

// B=64, I=4096, C=32, D=d=16
#define ITILES 256
#define IPB    16    // i's per itile

// ---------------------------------------------------------------------------
// R9 = R8 (coalesced W staging, proven 3.5 TB/s) minus the spill:
// 1024-thread blocks -> W[i] staged in 2 chunks of 16 KB -> R[2] (8 VGPRs
// instead of 16).  Grid = 256 = ONE block per CU; 16 waves; wave owns 4
// batches b = wave*4..+3 (full b coverage, no halving) -> W read from HBM
// exactly once per pass.
// Lane: c = lane&31, h = lane>>5 (D0 = 8h).
//
// LDS XOR layout (float4 units): word t of capsule c at slot t*32+(c^(t&31)).
//  - write (chunk k): c' = k*16+wave (uniform), t = lane ->
//    slot = lane*32 + ((lane&31)^c'); lanes permute over banks; h-halves
//    2-way alias (free).  ds_write_b128, conflict-free.
//  - read (j,dblk): t = h*32+u1, u1 = 4j+dblk ->
//    slot = h*1024 + u1*32 + (u1^c); same structure, conflict-free.
// Pipeline, ONE barrier/iter: ds_write R -> buf[ii&1]; barrier;
// global R <- W(i+1); compute buf[ii&1].  Write of buf[p] in iter ii only
// follows reads of buf[p] from iter ii-2, separated by barrier ii-1. Safe.
//
// x rides scalar loads (wave-uniform). v re-read each iter (anti-hoisted).
// USE_V=0: slab = sum_i u (uniform c folded into reduce scale).
// USE_V=1: p = u.vg -> softmax over c (no max-sub; |p| bounded) ->
//          slab = sum_i c_ij*u.
// Register accounting (the R2/R4/R8 lesson): u32+s_acc32+R8+xs16+v8+temps
// ~ 110 < 128 budget of launch_bounds(1024,4). WRITE_SIZE==33MB is the
// no-spill litmus.
// ---------------------------------------------------------------------------
template<int USE_V>
__global__ __launch_bounds__(1024, 4)   // 128-VGPR budget, 4 waves/SIMD
void pass_kernel(const float* __restrict__ Wg, const float* __restrict__ xg,
                 const float* __restrict__ vg, float* __restrict__ slab)
{
    __shared__ float4 lds_w[2][2048];   // 2 x 32 KB

    const int tid   = threadIdx.x;
    const int wave  = tid >> 6;          // 0..15
    const int lane  = tid & 63;
    const int c     = lane & 31;
    const int h     = lane >> 5;
    const int D0    = h * 8;
    const int itile = blockIdx.x;
    const int i0    = itile * IPB;
    const int b0    = wave * 4;          // 16 waves x 4 = all 64 batches
    const int b0u   = __builtin_amdgcn_readfirstlane(b0);

    const float4* W4 = (const float4*)Wg;

    // staging write slots (float4 units), one per chunk k
    int wslot[2];
    #pragma unroll
    for (int k = 0; k < 2; ++k) {
        const int cp = k * 16 + wave;           // = g>>6, uniform per wave
        wslot[k] = lane * 32 + ((lane & 31) ^ cp);
    }

    // ---- preload W(i0) coalesced into regs (8 VGPRs total)
    float4 R[2];
    #pragma unroll
    for (int k = 0; k < 2; ++k)
        R[k] = W4[(size_t)i0 * 2048 + k * 1024 + tid];

    float s_acc[8][4];   // [j][bb]
    #pragma unroll
    for (int j = 0; j < 8; ++j)
        #pragma unroll
        for (int bb = 0; bb < 4; ++bb) s_acc[j][bb] = 0.f;

    const float* vgl = vg;   // redefined opaquely each iter: blocks LICM hoist

    for (int ii = 0; ii < IPB; ++ii) {
        const int i = i0 + ii;

        // ---- stage W(i) regs -> buf[ii&1] (conflict-free swizzled writes)
        float4* bw = lds_w[ii & 1];
        #pragma unroll
        for (int k = 0; k < 2; ++k)
            bw[wslot[k]] = R[k];

        __syncthreads();   // buf[ii&1] complete

        // ---- issue coalesced loads for W(i+1); land during compute below
        if (ii + 1 < IPB) {
            #pragma unroll
            for (int k = 0; k < 2; ++k)
                R[k] = W4[(size_t)(i + 1) * 2048 + k * 1024 + tid];
        }

        const float4* br = lds_w[ii & 1];
        const float* xb = xg + (size_t)b0u * 65536 + (size_t)i * 16;

        if (USE_V == 0) {
            // ---- accumulate straight into s_acc (no u array)
            #pragma unroll
            for (int dblk = 0; dblk < 4; ++dblk) {
                float4 xs[4];   // wave-uniform -> scalar loads (SGPRs)
                #pragma unroll
                for (int bb = 0; bb < 4; ++bb)
                    xs[bb] = *(const float4*)(xb + (size_t)bb * 65536 + dblk * 4);
                #pragma unroll
                for (int j = 0; j < 8; ++j) {
                    const int u1 = 4 * j + dblk;
                    float4 wv = br[h * 1024 + u1 * 32 + (u1 ^ c)];
                    #pragma unroll
                    for (int bb = 0; bb < 4; ++bb) {
                        s_acc[j][bb] = fmaf(wv.x, xs[bb].x, s_acc[j][bb]);
                        s_acc[j][bb] = fmaf(wv.y, xs[bb].y, s_acc[j][bb]);
                        s_acc[j][bb] = fmaf(wv.z, xs[bb].z, s_acc[j][bb]);
                        s_acc[j][bb] = fmaf(wv.w, xs[bb].w, s_acc[j][bb]);
                    }
                }
            }
        } else {
            // ---- u_hat: u[j][bb] = sum_d W[c, D0+j, d] * x[b0+bb, i, d]
            float u[8][4];
            #pragma unroll
            for (int j = 0; j < 8; ++j)
                #pragma unroll
                for (int bb = 0; bb < 4; ++bb) u[j][bb] = 0.f;

            #pragma unroll
            for (int dblk = 0; dblk < 4; ++dblk) {
                float4 xs[4];
                #pragma unroll
                for (int bb = 0; bb < 4; ++bb)
                    xs[bb] = *(const float4*)(xb + (size_t)bb * 65536 + dblk * 4);
                #pragma unroll
                for (int j = 0; j < 8; ++j) {
                    const int u1 = 4 * j + dblk;
                    float4 wv = br[h * 1024 + u1 * 32 + (u1 ^ c)];
                    #pragma unroll
                    for (int bb = 0; bb < 4; ++bb) {
                        u[j][bb] = fmaf(wv.x, xs[bb].x, u[j][bb]);
                        u[j][bb] = fmaf(wv.y, xs[bb].y, u[j][bb]);
                        u[j][bb] = fmaf(wv.z, xs[bb].z, u[j][bb]);
                        u[j][bb] = fmaf(wv.w, xs[bb].w, u[j][bb]);
                    }
                }
            }

            // ---- v re-read (L2-hot, loop-invariant but NOT reg-hoisted)
            asm volatile("" : "+r"(vgl));
            // ---- routing: p -> softmax over c (no max-sub) -> s_acc += c_ij*u
            #pragma unroll
            for (int bb = 0; bb < 4; ++bb) {
                const float* vp = vgl + (size_t)(b0 + bb) * 512 + (size_t)(c * 16 + D0);
                const float4 va = *(const float4*)vp;
                const float4 vb = *(const float4*)(vp + 4);
                float p = 0.f;
                p = fmaf(u[0][bb], va.x, p); p = fmaf(u[1][bb], va.y, p);
                p = fmaf(u[2][bb], va.z, p); p = fmaf(u[3][bb], va.w, p);
                p = fmaf(u[4][bb], vb.x, p); p = fmaf(u[5][bb], vb.y, p);
                p = fmaf(u[6][bb], vb.z, p); p = fmaf(u[7][bb], vb.w, p);
                p += __shfl_xor(p, 32);   // combine D-halves (lanes l, l^32 share c)
                // |p| <= |u||v| ~ 12 -> exp safe without max subtraction
                float e = __expf(p);
                float t = e;
                t += __shfl_xor(t, 16);
                t += __shfl_xor(t, 8);
                t += __shfl_xor(t, 4);
                t += __shfl_xor(t, 2);
                t += __shfl_xor(t, 1);
                float cij = __fdividef(e, t);
                #pragma unroll
                for (int j = 0; j < 8; ++j)
                    s_acc[j][bb] = fmaf(cij, u[j][bb], s_acc[j][bb]);
            }
        }
    }

    // ---- write per-itile partial slab (contiguous per (itile,b))
    float4* slab4 = (float4*)slab;
    #pragma unroll
    for (int bb = 0; bb < 4; ++bb) {
        const int b = b0 + bb;
        size_t base = (size_t)itile * 8192 + (size_t)b * 128 + (size_t)(c * 4 + 2 * h);
        float4 lo = {s_acc[0][bb], s_acc[1][bb], s_acc[2][bb], s_acc[3][bb]};
        float4 hi = {s_acc[4][bb], s_acc[5][bb], s_acc[6][bb], s_acc[7][bb]};
        slab4[base]     = lo;
        slab4[base + 1] = hi;
    }
}

// ---------------------------------------------------------------------------
// Reduce 256 slabs -> s_j[b,c,D], squash -> out. If v1in != null, also emit
// vsum = out + v1in (pre-summed v12 for the next pass's u.(v1+v2) fold).
// ---------------------------------------------------------------------------
__global__ __launch_bounds__(256)
void reduce_squash(const float* __restrict__ slab, float* __restrict__ out, float scale,
                   const float* __restrict__ v1in, float* __restrict__ vsum)
{
    const int o = blockIdx.x * 256 + threadIdx.x;   // o = b*512 + c*16 + D
    float a[16];
    #pragma unroll
    for (int k = 0; k < 16; ++k) a[k] = 0.f;
    for (int g = 0; g < 16; ++g) {
        #pragma unroll
        for (int k = 0; k < 16; ++k)
            a[k] += slab[(size_t)(g * 16 + k) * 32768 + o];
    }
    float s = 0.f;
    #pragma unroll
    for (int k = 0; k < 16; ++k) s += a[k];
    s *= scale;
    float t = s * s;
    t += __shfl_xor(t, 1);
    t += __shfl_xor(t, 2);
    t += __shfl_xor(t, 4);
    t += __shfl_xor(t, 8);
    float r = s / (1.0f + t) / sqrtf(t + 1e-9f);
    out[o] = r;
    if (v1in) vsum[o] = r + v1in[o];
}

extern "C" void kernel_launch(void* const* d_in, const int* in_sizes, int n_in,
                              void* d_out, int out_size, void* d_ws, size_t ws_size,
                              hipStream_t stream)
{
    const float* x = (const float*)d_in[0];   // [64, 4096, 16]
    const float* W = (const float*)d_in[1];   // [1, 4096, 32, 16, 16]

    float* slab = (float*)d_ws;                     // 256 * 32768 floats = 32 MB
    float* v1   = slab + (size_t)ITILES * 32768;
    float* v2   = v1 + 32768;
    float* v12  = v2 + 32768;
    float* out  = (float*)d_out;

    // iter 1: uniform c (1/32 folded into reduce scale)
    hipLaunchKernelGGL((pass_kernel<0>), dim3(ITILES), dim3(1024), 0, stream, W, x, (const float*)nullptr, slab);
    hipLaunchKernelGGL(reduce_squash,    dim3(128),    dim3(256),  0, stream, slab, v1, 1.0f / 32.0f, (const float*)nullptr, (float*)nullptr);
    // iter 2: p = u.v1 ; reduce also emits v12 = v1 + v2
    hipLaunchKernelGGL((pass_kernel<1>), dim3(ITILES), dim3(1024), 0, stream, W, x, v1, slab);
    hipLaunchKernelGGL(reduce_squash,    dim3(128),    dim3(256),  0, stream, slab, v2, 1.0f, v1, v12);
    // iter 3: p = u.v1 + u.v2 = u.v12
    hipLaunchKernelGGL((pass_kernel<1>), dim3(ITILES), dim3(1024), 0, stream, W, x, v12, slab);
    hipLaunchKernelGGL(reduce_squash,    dim3(128),    dim3(256),  0, stream, slab, out, 1.0f, (const float*)nullptr, (float*)nullptr);
}

// Round 10
// 500.081 us; speedup vs baseline: 1.6110x; 1.5784x over previous
//
#include <hip/hip_runtime.h>
#include <math.h>

// B=64, I=4096, C=32, D=d=16
#define ITILES 256
#define IPB    16

typedef __bf16 bf16x8 __attribute__((ext_vector_type(8)));
typedef float  f32x16 __attribute__((ext_vector_type(16)));

__device__ inline unsigned short f2bf(float f) {   // rne bf16 truncation
    unsigned int x = __float_as_uint(f);
    x += 0x7fff + ((x >> 16) & 1);
    return (unsigned short)(x >> 16);
}
__device__ inline float bf2f(unsigned short u) {
    return __uint_as_float(((unsigned int)u) << 16);
}
__device__ inline uint4 pack8(const unsigned short* o) {
    uint4 p;
    p.x = o[0] | ((unsigned)o[1] << 16);
    p.y = o[2] | ((unsigned)o[3] << 16);
    p.z = o[4] | ((unsigned)o[5] << 16);
    p.w = o[6] | ((unsigned)o[7] << 16);
    return p;
}

// ---------------------------------------------------------------------------
// prep_w: W fp32 [i][c][D][d] -> Wp bf16x3 in A-fragment lane order.
// Fragment convention (32x32x16): A[m = lane&31][k = (lane>>5)*8 + j].
// M-row r (in tile m): c = 2m + ((r>>2)&1), D = (r&3) + 4*(r>>3)
//   (chosen so C-frag reg == D and lane-half == c_local).
// Wp[(i*3 + a)*8192 + m*512 + lane*8 + j]
// ---------------------------------------------------------------------------
__global__ __launch_bounds__(256) void prep_w(const float* __restrict__ W,
                                              unsigned short* __restrict__ Wp)
{
    const int i = blockIdx.x;
    const int t = threadIdx.x;
    #pragma unroll
    for (int s = 0; s < 4; ++s) {
        const int e  = t * 32 + s * 8;          // element base within (i, term)
        const int l  = (e >> 3) & 63;
        const int m  = e >> 9;
        const int r  = l & 31, kh = l >> 5;
        const int c  = 2 * m + ((r >> 2) & 1);
        const int D  = (r & 3) + 4 * (r >> 3);
        const float4* s4 = (const float4*)(W + ((((size_t)i * 32 + c) * 16 + D) * 16 + kh * 8));
        float4 wa = s4[0], wb = s4[1];
        float wv[8] = {wa.x, wa.y, wa.z, wa.w, wb.x, wb.y, wb.z, wb.w};
        unsigned short o1[8], o2[8], o3[8];
        #pragma unroll
        for (int j = 0; j < 8; ++j) {
            float w = wv[j];
            o1[j] = f2bf(w);            float f1 = bf2f(o1[j]);
            o2[j] = f2bf(w - f1);       float f2 = bf2f(o2[j]);
            o3[j] = f2bf(w - f1 - f2);
        }
        unsigned short* dst = Wp + (size_t)i * 24576 + e;
        *(uint4*)(dst)         = pack8(o1);
        *(uint4*)(dst + 8192)  = pack8(o2);
        *(uint4*)(dst + 16384) = pack8(o3);
    }
}

// ---------------------------------------------------------------------------
// prep_x: x fp32 [b][i][d] -> Xp bf16x3 in B-fragment lane order.
// B[k = (lane>>5)*8 + j][n = lane&31 (+32*ntile)].
// Xp[a*4096*1024 + i*1024 + kh*512 + b*8 + j]
// ---------------------------------------------------------------------------
__global__ __launch_bounds__(128) void prep_x(const float* __restrict__ x,
                                              unsigned short* __restrict__ Xp)
{
    const int i = blockIdx.x;
    const int t = threadIdx.x;           // 128 = 64 b x 2 kh
    const int b = t >> 1, kh = t & 1;
    const float4* s4 = (const float4*)(x + ((size_t)b * 4096 + i) * 16 + kh * 8);
    float4 wa = s4[0], wb = s4[1];
    float wv[8] = {wa.x, wa.y, wa.z, wa.w, wb.x, wb.y, wb.z, wb.w};
    unsigned short o1[8], o2[8], o3[8];
    #pragma unroll
    for (int j = 0; j < 8; ++j) {
        float w = wv[j];
        o1[j] = f2bf(w);            float f1 = bf2f(o1[j]);
        o2[j] = f2bf(w - f1);       float f2 = bf2f(o2[j]);
        o3[j] = f2bf(w - f1 - f2);
    }
    unsigned short* dst = Xp + (size_t)i * 1024 + kh * 512 + b * 8;
    *(uint4*)(dst)            = pack8(o1);
    *(uint4*)(dst + 4194304)  = pack8(o2);
    *(uint4*)(dst + 8388608)  = pack8(o3);
}

// ---------------------------------------------------------------------------
// Pass kernel, MFMA edition. Grid=256 (1 block/CU), block=1024 (16 waves).
// Wave = M-tile mt (16 tiles x 32 rows = all 512 (c,D)); N = 2 tiles (64 b).
// Per i: 3 A-frags + 6 B-frags loaded DIRECT from global (prep order ->
// coalesced, no LDS staging, no staging barrier). 12 MFMAs (6 terms x 2 nt)
// emulate fp32: u = W1X1 + (W1X2+W2X1) + (W1X3+W2X2+W3X1), err ~2^-24.
// C-frag element (reg q, lane): b = 32*nt + (lane&31), c = 2mt + (lane>>5),
// D = q  (by prep row-order choice).
// Routing (USE_V=1): p = sum_D u*v (v from 128KB swizzled LDS, i-invariant),
// p -> LDS -> softmax over c (wave-butterfly, 4 b/wave) -> cij -> s += cij*u.
// Two barriers/i, no vmcnt drain attached.
// Pass0 (USE_V=0): MFMA directly into s-accumulators, zero barriers.
// ---------------------------------------------------------------------------
template<int USE_V>
__global__ __launch_bounds__(1024, 4)
void pass_kernel(const unsigned short* __restrict__ Wp,
                 const unsigned short* __restrict__ Xp,
                 const float* __restrict__ vg,
                 float* __restrict__ slab)
{
    __shared__ float4 vt[8192];          // 128 KB  v[b][cd] xor-swizzled
    __shared__ float  p_lds[32 * 65];    // p[c][b], pitch 65 (conflict-free both axes)
    __shared__ float  cij_lds[32 * 65];

    const int tid   = threadIdx.x;
    const int mt    = tid >> 6;          // wave index = M-tile
    const int lane  = tid & 63;
    const int l31   = lane & 31;
    const int h     = lane >> 5;
    const int cA    = 2 * mt + h;        // this lane's capsule index in its frags
    const int itile = blockIdx.x;
    const int i0    = itile * IPB;

    if (USE_V) {
        // stage v (i-invariant) once: slot = b*128 + (cd ^ (b&31)), float4 units
        const float4* v4 = (const float4*)vg;
        #pragma unroll
        for (int k = 0; k < 8; ++k) {
            int idx = k * 1024 + tid;
            int b = idx >> 7, cd = idx & 127;
            vt[b * 128 + (cd ^ (b & 31))] = v4[idx];
        }
        __syncthreads();
    }

    f32x16 s0, s1;
    #pragma unroll
    for (int q = 0; q < 16; ++q) { s0[q] = 0.f; s1[q] = 0.f; }

    for (int ii = 0; ii < IPB; ++ii) {
        const int i = i0 + ii;
        // ---- A fragments (3 terms), direct coalesced global
        const unsigned short* ab = Wp + (size_t)i * 24576 + mt * 512 + lane * 8;
        uint4 a1 = *(const uint4*)(ab);
        uint4 a2 = *(const uint4*)(ab + 8192);
        uint4 a3 = *(const uint4*)(ab + 16384);
        // ---- B fragments (3 terms x 2 n-tiles), direct global
        const unsigned short* bb = Xp + (size_t)i * 1024 + (size_t)h * 512 + l31 * 8;
        uint4 b10 = *(const uint4*)(bb);
        uint4 b11 = *(const uint4*)(bb + 256);
        uint4 b20 = *(const uint4*)(bb + 4194304);
        uint4 b21 = *(const uint4*)(bb + 4194304 + 256);
        uint4 b30 = *(const uint4*)(bb + 8388608);
        uint4 b31 = *(const uint4*)(bb + 8388608 + 256);

        #define MF(A_, B_, C_) __builtin_amdgcn_mfma_f32_32x32x16_bf16( \
            __builtin_bit_cast(bf16x8, A_), __builtin_bit_cast(bf16x8, B_), C_, 0, 0, 0)

        if (USE_V == 0) {
            // pure accumulate: s += W.x  (6 terms, 2 n-tiles, interleaved chains)
            s0 = MF(a1, b10, s0); s1 = MF(a1, b11, s1);
            s0 = MF(a2, b10, s0); s1 = MF(a2, b11, s1);
            s0 = MF(a1, b20, s0); s1 = MF(a1, b21, s1);
            s0 = MF(a3, b10, s0); s1 = MF(a3, b11, s1);
            s0 = MF(a2, b20, s0); s1 = MF(a2, b21, s1);
            s0 = MF(a1, b30, s0); s1 = MF(a1, b31, s1);
        } else {
            f32x16 u0, u1;
            #pragma unroll
            for (int q = 0; q < 16; ++q) { u0[q] = 0.f; u1[q] = 0.f; }
            u0 = MF(a1, b10, u0); u1 = MF(a1, b11, u1);
            u0 = MF(a2, b10, u0); u1 = MF(a2, b11, u1);
            u0 = MF(a1, b20, u0); u1 = MF(a1, b21, u1);
            u0 = MF(a3, b10, u0); u1 = MF(a3, b11, u1);
            u0 = MF(a2, b20, u0); u1 = MF(a2, b21, u1);
            u0 = MF(a1, b30, u0); u1 = MF(a1, b31, u1);

            // ---- p = sum_D u*v  (full D per lane; reg q == D)
            #pragma unroll
            for (int nt = 0; nt < 2; ++nt) {
                const f32x16& uu = nt ? u1 : u0;
                const int b = nt * 32 + l31;
                float p = 0.f;
                #pragma unroll
                for (int dblk = 0; dblk < 4; ++dblk) {
                    float4 vv = vt[b * 128 + ((cA * 4 + dblk) ^ l31)];
                    p = fmaf(uu[dblk * 4 + 0], vv.x, p);
                    p = fmaf(uu[dblk * 4 + 1], vv.y, p);
                    p = fmaf(uu[dblk * 4 + 2], vv.z, p);
                    p = fmaf(uu[dblk * 4 + 3], vv.w, p);
                }
                p_lds[cA * 65 + b] = p;
            }
            __syncthreads();
            // ---- softmax over c: wave mt owns b = mt*4 + r*2 + h; lanes = c
            #pragma unroll
            for (int r2 = 0; r2 < 2; ++r2) {
                const int b = mt * 4 + r2 * 2 + h;
                float e = __expf(p_lds[l31 * 65 + b]);   // |p| bounded, no max-sub
                float t = e;
                t += __shfl_xor(t, 16); t += __shfl_xor(t, 8);
                t += __shfl_xor(t, 4);  t += __shfl_xor(t, 2);
                t += __shfl_xor(t, 1);
                cij_lds[l31 * 65 + b] = __fdividef(e, t);
            }
            __syncthreads();
            // ---- s += cij * u
            #pragma unroll
            for (int nt = 0; nt < 2; ++nt) {
                const f32x16& uu = nt ? u1 : u0;
                f32x16&       ss = nt ? s1 : s0;
                const int b = nt * 32 + l31;
                const float cij = cij_lds[cA * 65 + b];
                #pragma unroll
                for (int q = 0; q < 16; ++q) ss[q] = fmaf(cij, uu[q], ss[q]);
            }
        }
        #undef MF
    }

    // ---- slab[itile][b][c][D] partial write
    float4* slab4 = (float4*)slab;
    #pragma unroll
    for (int nt = 0; nt < 2; ++nt) {
        const f32x16& ss = nt ? s1 : s0;
        const int b = nt * 32 + l31;
        size_t base = ((size_t)itile * 64 + b) * 128 + cA * 4;
        #pragma unroll
        for (int dblk = 0; dblk < 4; ++dblk) {
            float4 o = {ss[dblk * 4 + 0], ss[dblk * 4 + 1], ss[dblk * 4 + 2], ss[dblk * 4 + 3]};
            slab4[base + dblk] = o;
        }
    }
}

// ---------------------------------------------------------------------------
// Reduce 256 slabs -> s_j[b,c,D], squash -> out; optional v12 = out + v1in.
// ---------------------------------------------------------------------------
__global__ __launch_bounds__(256)
void reduce_squash(const float* __restrict__ slab, float* __restrict__ out, float scale,
                   const float* __restrict__ v1in, float* __restrict__ vsum)
{
    const int o = blockIdx.x * 256 + threadIdx.x;   // o = b*512 + c*16 + D
    float a[16];
    #pragma unroll
    for (int k = 0; k < 16; ++k) a[k] = 0.f;
    for (int g = 0; g < 16; ++g) {
        #pragma unroll
        for (int k = 0; k < 16; ++k)
            a[k] += slab[(size_t)(g * 16 + k) * 32768 + o];
    }
    float s = 0.f;
    #pragma unroll
    for (int k = 0; k < 16; ++k) s += a[k];
    s *= scale;
    float t = s * s;
    t += __shfl_xor(t, 1);
    t += __shfl_xor(t, 2);
    t += __shfl_xor(t, 4);
    t += __shfl_xor(t, 8);
    float r = s / (1.0f + t) / sqrtf(t + 1e-9f);
    out[o] = r;
    if (v1in) vsum[o] = r + v1in[o];
}

extern "C" void kernel_launch(void* const* d_in, const int* in_sizes, int n_in,
                              void* d_out, int out_size, void* d_ws, size_t ws_size,
                              hipStream_t stream)
{
    const float* x = (const float*)d_in[0];   // [64, 4096, 16]
    const float* W = (const float*)d_in[1];   // [1, 4096, 32, 16, 16]

    // workspace: slab 32MB | v1,v2,v12 384KB | Wp 192MB bf16x3 | Xp 24MB bf16x3
    float* slab = (float*)d_ws;
    float* v1   = slab + (size_t)ITILES * 32768;
    float* v2   = v1 + 32768;
    float* v12  = v2 + 32768;
    unsigned short* Wp = (unsigned short*)(v12 + 32768);
    unsigned short* Xp = Wp + (size_t)4096 * 24576;
    float* out  = (float*)d_out;

    hipLaunchKernelGGL(prep_w, dim3(4096), dim3(256), 0, stream, W, Wp);
    hipLaunchKernelGGL(prep_x, dim3(4096), dim3(128), 0, stream, x, Xp);

    // iter 1: uniform c (1/32 folded into reduce scale)
    hipLaunchKernelGGL((pass_kernel<0>), dim3(ITILES), dim3(1024), 0, stream, Wp, Xp, (const float*)nullptr, slab);
    hipLaunchKernelGGL(reduce_squash,    dim3(128),    dim3(256),  0, stream, slab, v1, 1.0f / 32.0f, (const float*)nullptr, (float*)nullptr);
    // iter 2: p = u.v1 ; reduce also emits v12 = v1 + v2
    hipLaunchKernelGGL((pass_kernel<1>), dim3(ITILES), dim3(1024), 0, stream, Wp, Xp, v1, slab);
    hipLaunchKernelGGL(reduce_squash,    dim3(128),    dim3(256),  0, stream, slab, v2, 1.0f, v1, v12);
    // iter 3: p = u.(v1+v2) = u.v12
    hipLaunchKernelGGL((pass_kernel<1>), dim3(ITILES), dim3(1024), 0, stream, Wp, Xp, v12, slab);
    hipLaunchKernelGGL(reduce_squash,    dim3(128),    dim3(256),  0, stream, slab, out, 1.0f, (const float*)nullptr, (float*)nullptr);
}